// Round 2
// baseline (81.023 us; speedup 1.0000x reference)
//
#include <hip/hip_runtime.h>
#include <math.h>

// PointOnSurfaceLoss: B=8, M=512, N=8192
//   keypoint: (B,3,M) fp32, pc: (B,3,N) fp32, sn: (B,3,N) fp32
//   out: (B,M,1,1) fp32 = (sn_sel . d_unit)^2, sel = argmin_n ||kp - pc_n||
//
// R3 theory: R1/R2 identical at ~68.7 total despite 2x occupancy delta =>
// kernel region is bound by a wave-count-invariant resource. Candidate: L2
// read traffic. R2: 128 blocks/batch x 98 KB pc panel = 100 MB through L2
// (~28 us at ~3.5 TB/s effective) vs a 3.8 us VALU floor.
// R3: KPB 4 -> 16 (each pc point in registers serves 16 keypoints):
//   256 blocks x 1024 thr (16 waves, 1 block/CU, 4 waves/SIMD), 25 MB traffic.
// Keypoint coords are block-uniform -> 48 SGPRs. Per-thread: 8 points x 16
// kps. Argmin semantics unchanged (strict <, smaller-index tie-break).

#define PB 8
#define PM 512
#define PN 8192
#define KPB 16
#define TPB 1024
#define NWAVE (TPB / 64)
#define PEPS 1e-7f

__device__ __forceinline__ void combine_min(float& d2, int& idx, float od2, int oidx) {
    if (od2 < d2 || (od2 == d2 && oidx < idx)) { d2 = od2; idx = oidx; }
}

__global__ __launch_bounds__(TPB, 4) void posloss_kernel(
    const float* __restrict__ keypoint,  // B*3*M
    const float* __restrict__ pc,        // B*3*N
    const float* __restrict__ sn,        // B*3*N
    float* __restrict__ out)             // B*M
{
    const int blk = blockIdx.x;              // 0 .. B*M/KPB - 1  (256)
    const int b   = blk >> 5;                // 32 blocks per batch (512/16)
    const int m0  = (blk & 31) * KPB;
    const int tid = threadIdx.x;

    // block-uniform keypoint coords -> scalar loads (SGPRs)
    const float* kp = keypoint + b * 3 * PM;
    float kx[KPB], ky[KPB], kz[KPB];
    #pragma unroll
    for (int k = 0; k < KPB; ++k) {
        kx[k] = kp[0 * PM + m0 + k];
        ky[k] = kp[1 * PM + m0 + k];
        kz[k] = kp[2 * PM + m0 + k];
    }

    const float* pcx = pc + b * 3 * PN;
    const float* pcy = pcx + PN;
    const float* pcz = pcy + PN;

    float best[KPB];
    int   bidx[KPB];
    #pragma unroll
    for (int k = 0; k < KPB; ++k) { best[k] = 3.4e38f; bidx[k] = 0; }

    const float4* px4 = (const float4*)pcx;
    const float4* py4 = (const float4*)pcy;
    const float4* pz4 = (const float4*)pcz;

    #pragma unroll
    for (int it = 0; it < PN / (TPB * 4); ++it) {   // 2 iterations
        const int v  = it * TPB + tid;              // float4 index
        const int n0 = v * 4;                       // point index of .x
        const float4 x4 = px4[v];
        const float4 y4 = py4[v];
        const float4 z4 = pz4[v];
        const float xs[4] = {x4.x, x4.y, x4.z, x4.w};
        const float ys[4] = {y4.x, y4.y, y4.z, y4.w};
        const float zs[4] = {z4.x, z4.y, z4.z, z4.w};
        #pragma unroll
        for (int j = 0; j < 4; ++j) {
            const float px = xs[j], py = ys[j], pz = zs[j];
            #pragma unroll
            for (int k = 0; k < KPB; ++k) {
                const float dx = kx[k] - px;
                const float dy = ky[k] - py;
                const float dz = kz[k] - pz;
                const float d2 = fmaf(dz, dz, fmaf(dy, dy, dx * dx));
                if (d2 < best[k]) { best[k] = d2; bidx[k] = n0 + j; }
            }
        }
    }

    // Wave64 shuffle reduction per keypoint (tie-break: smaller index wins)
    #pragma unroll
    for (int k = 0; k < KPB; ++k) {
        #pragma unroll
        for (int off = 32; off > 0; off >>= 1) {
            float od2  = __shfl_down(best[k], off);
            int   oidx = __shfl_down(bidx[k], off);
            combine_min(best[k], bidx[k], od2, oidx);
        }
    }

    __shared__ float s_d2[NWAVE][KPB];
    __shared__ int   s_idx[NWAVE][KPB];
    const int wave = tid >> 6;
    const int lane = tid & 63;
    if (lane == 0) {
        #pragma unroll
        for (int k = 0; k < KPB; ++k) { s_d2[wave][k] = best[k]; s_idx[wave][k] = bidx[k]; }
    }
    __syncthreads();

    if (tid < KPB) {
        const int k = tid;
        float bd = s_d2[0][k];
        int   bi = s_idx[0][k];
        #pragma unroll
        for (int w = 1; w < NWAVE; ++w) combine_min(bd, bi, s_d2[w][k], s_idx[w][k]);

        const float px = pcx[bi], py = pcy[bi], pz = pcz[bi];
        const float* snb = sn + b * 3 * PN;
        const float sx = snb[0 * PN + bi];
        const float sy = snb[1 * PN + bi];
        const float sz = snb[2 * PN + bi];

        const float dx = kx[k] - px, dy = ky[k] - py, dz = kz[k] - pz;
        const float dn = sqrtf(dx * dx + dy * dy + dz * dz);
        const float inv = 1.0f / (dn + PEPS);
        const float dot = sx * (dx * inv) + sy * (dy * inv) + sz * (dz * inv);
        out[b * PM + m0 + k] = dot * dot;
    }
}

extern "C" void kernel_launch(void* const* d_in, const int* in_sizes, int n_in,
                              void* d_out, int out_size, void* d_ws, size_t ws_size,
                              hipStream_t stream) {
    const float* keypoint = (const float*)d_in[0];  // B*3*M
    const float* pc       = (const float*)d_in[1];  // B*3*N
    const float* sn       = (const float*)d_in[2];  // B*3*N
    float* out            = (float*)d_out;          // B*M

    posloss_kernel<<<(PB * PM) / KPB, TPB, 0, stream>>>(keypoint, pc, sn, out);
}

// Round 3
// 67.203 us; speedup vs baseline: 1.2056x; 1.2056x over previous
//
#include <hip/hip_runtime.h>
#include <math.h>

// PointOnSurfaceLoss: B=8, M=512, N=8192
//   keypoint: (B,3,M) fp32, pc: (B,3,N) fp32, sn: (B,3,N) fp32
//   out: (B,M,1,1) fp32 = (sn_sel . d_unit)^2, sel = argmin_n ||kp - pc_n||
//
// R4: discriminating probe. R0/R1/R2 all land at 68.6-68.9 total while the
// timed region contains a fixed 40.2 us 256MB poison-fill (84% HBM peak).
// Kernel VALU floor is ~4 us; no mechanism found for a 28 us kernel. Theory:
// residual ~23 us is fixed harness glue, kernel is already ~5 us.
// This probe reverts R3 (KPB back to 4, small reduction tail) and maximizes
// everything cheaply: 256 thr/block, __launch_bounds__(256,8) -> <=64 VGPR,
// 8 blocks/CU, 32 waves/CU (independent blocks, no 512-wide sync coupling),
// explicit 1-round-ahead prefetch of the 3 float4 loads. Math identical to
// R2 (sub-based d2, fmaf, strict <, smaller-index tie-break) -> absmax 0.
// Branch prediction: unchanged ~68.6 => floor is structural => ROOFLINE.

#define PB 8
#define PM 512
#define PN 8192
#define KPB 4
#define TPB 256
#define NWAVE (TPB / 64)
#define NIT (PN / (TPB * 4))   // 8 rounds of float4 per thread
#define PEPS 1e-7f

__device__ __forceinline__ void combine_min(float& d2, int& idx, float od2, int oidx) {
    if (od2 < d2 || (od2 == d2 && oidx < idx)) { d2 = od2; idx = oidx; }
}

__global__ __launch_bounds__(TPB, 8) void posloss_kernel(
    const float* __restrict__ keypoint,  // B*3*M
    const float* __restrict__ pc,        // B*3*N
    const float* __restrict__ sn,        // B*3*N
    float* __restrict__ out)             // B*M
{
    const int blk = blockIdx.x;              // 0 .. B*M/KPB - 1  (1024)
    const int b   = blk >> 7;                // 128 blocks per batch (512/4)
    const int m0  = (blk & 127) * KPB;
    const int tid = threadIdx.x;

    // wave-uniform keypoint coords -> SGPRs
    const float* kp = keypoint + b * 3 * PM;
    float kx[KPB], ky[KPB], kz[KPB];
    #pragma unroll
    for (int k = 0; k < KPB; ++k) {
        kx[k] = kp[0 * PM + m0 + k];
        ky[k] = kp[1 * PM + m0 + k];
        kz[k] = kp[2 * PM + m0 + k];
    }

    const float* pcx = pc + b * 3 * PN;
    const float* pcy = pcx + PN;
    const float* pcz = pcy + PN;

    float best[KPB];
    int   bidx[KPB];
    #pragma unroll
    for (int k = 0; k < KPB; ++k) { best[k] = 3.4e38f; bidx[k] = 0; }

    const float4* px4 = (const float4*)pcx;
    const float4* py4 = (const float4*)pcy;
    const float4* pz4 = (const float4*)pcz;

    // software pipeline: loads for round it+1 issued before compute of round it
    float4 nx = px4[tid];
    float4 ny = py4[tid];
    float4 nz = pz4[tid];

    #pragma unroll
    for (int it = 0; it < NIT; ++it) {
        const float4 cx = nx, cy = ny, cz = nz;
        if (it + 1 < NIT) {
            const int v = (it + 1) * TPB + tid;
            nx = px4[v]; ny = py4[v]; nz = pz4[v];
        }
        const int n0 = (it * TPB + tid) * 4;
        const float xs[4] = {cx.x, cx.y, cx.z, cx.w};
        const float ys[4] = {cy.x, cy.y, cy.z, cy.w};
        const float zs[4] = {cz.x, cz.y, cz.z, cz.w};
        #pragma unroll
        for (int j = 0; j < 4; ++j) {
            const float px = xs[j], py = ys[j], pz = zs[j];
            #pragma unroll
            for (int k = 0; k < KPB; ++k) {
                const float dx = kx[k] - px;
                const float dy = ky[k] - py;
                const float dz = kz[k] - pz;
                const float d2 = fmaf(dz, dz, fmaf(dy, dy, dx * dx));
                if (d2 < best[k]) { best[k] = d2; bidx[k] = n0 + j; }
            }
        }
    }

    // Wave64 shuffle reduction per keypoint (tie-break: smaller index wins)
    #pragma unroll
    for (int k = 0; k < KPB; ++k) {
        #pragma unroll
        for (int off = 32; off > 0; off >>= 1) {
            float od2  = __shfl_down(best[k], off);
            int   oidx = __shfl_down(bidx[k], off);
            combine_min(best[k], bidx[k], od2, oidx);
        }
    }

    __shared__ float s_d2[NWAVE][KPB];
    __shared__ int   s_idx[NWAVE][KPB];
    const int wave = tid >> 6;
    const int lane = tid & 63;
    if (lane == 0) {
        #pragma unroll
        for (int k = 0; k < KPB; ++k) { s_d2[wave][k] = best[k]; s_idx[wave][k] = bidx[k]; }
    }
    __syncthreads();

    if (tid < KPB) {
        const int k = tid;
        float bd = s_d2[0][k];
        int   bi = s_idx[0][k];
        #pragma unroll
        for (int w = 1; w < NWAVE; ++w) combine_min(bd, bi, s_d2[w][k], s_idx[w][k]);

        const float px = pcx[bi], py = pcy[bi], pz = pcz[bi];
        const float* snb = sn + b * 3 * PN;
        const float sx = snb[0 * PN + bi];
        const float sy = snb[1 * PN + bi];
        const float sz = snb[2 * PN + bi];

        const float dx = kx[k] - px, dy = ky[k] - py, dz = kz[k] - pz;
        const float dn = sqrtf(dx * dx + dy * dy + dz * dz);
        const float inv = 1.0f / (dn + PEPS);
        const float dot = sx * (dx * inv) + sy * (dy * inv) + sz * (dz * inv);
        out[b * PM + m0 + k] = dot * dot;
    }
}

extern "C" void kernel_launch(void* const* d_in, const int* in_sizes, int n_in,
                              void* d_out, int out_size, void* d_ws, size_t ws_size,
                              hipStream_t stream) {
    const float* keypoint = (const float*)d_in[0];  // B*3*M
    const float* pc       = (const float*)d_in[1];  // B*3*N
    const float* sn       = (const float*)d_in[2];  // B*3*N
    float* out            = (float*)d_out;          // B*M

    posloss_kernel<<<(PB * PM) / KPB, TPB, 0, stream>>>(keypoint, pc, sn, out);
}